// Round 7
// baseline (197.509 us; speedup 1.0000x reference)
//
#include <hip/hip_runtime.h>
#include <hip/hip_bf16.h>

// ---------------------------------------------------------------------------
// Problem constants
// ---------------------------------------------------------------------------
#define B_  2
#define N_  2048
#define D_  1024
#define H_  16
#define DH_ 64
#define BN_ROWS (B_ * N_)   // 4096
#define EPS_ 1e-5f
#define QKV_N 3072          // fused [Q | K | V] output width

typedef __attribute__((ext_vector_type(8))) short bf16x8_t;
typedef __attribute__((ext_vector_type(4))) short bf16x4_t;
typedef __attribute__((ext_vector_type(4))) float f32x4_t;

// K=16 bf16 MFMA (v_mfma_f32_16x16x16_bf16): A/B = 4 bf16 (k = quad*4+reg),
// C/D = 4 f32 (row = quad*4+r, col = l16).
#define MFMA16(a, b, c) __builtin_amdgcn_mfma_f32_16x16x16bf16_1k(a, b, c, 0, 0, 0)
#define MFMA32(a, b, c) __builtin_amdgcn_mfma_f32_16x16x32_bf16(a, b, c, 0, 0, 0)

typedef const unsigned int __attribute__((address_space(1)))* gas_ptr;
typedef unsigned int __attribute__((address_space(3)))* las_ptr;

// async global->LDS, 16B per lane, dest = wave-uniform base + lane*16
__device__ __forceinline__ void async16(const unsigned short* g, unsigned short* l) {
    __builtin_amdgcn_global_load_lds((gas_ptr)g, (las_ptr)l, 16, 0, 0);
}

__device__ __forceinline__ unsigned short f2bf(float f) {
    unsigned int u = __float_as_uint(f);
    unsigned int r = u + 0x7FFFu + ((u >> 16) & 1u);   // round-to-nearest-even
    return (unsigned short)(r >> 16);
}

// pack two f32 -> bf16x2
__device__ __forceinline__ unsigned int pk2bf(float a, float b) {
    __hip_bfloat162 t = __float22bfloat162_rn(float2{a, b});
    return *(unsigned int*)&t;
}

// ---------------------------------------------------------------------------
// Kernel 1: fused dual LayerNorm + all-weight bf16 transposes (one dispatch).
// blocks [0,4096): LN rows. blocks [4096,8192): weight transpose tiles.
// ---------------------------------------------------------------------------
__global__ __launch_bounds__(256) void ln_wt_kernel(
    const float* __restrict__ x,
    const float* __restrict__ g1, const float* __restrict__ b1,
    const float* __restrict__ g2, const float* __restrict__ b2,
    const float* __restrict__ Wq, const float* __restrict__ Wkv,
    const float* __restrict__ Wo,
    unsigned short* __restrict__ xn, unsigned short* __restrict__ cn,
    unsigned short* __restrict__ wqkvT, unsigned short* __restrict__ woT) {
    const int bid = blockIdx.x;
    const int tid = threadIdx.x;

    if (bid < BN_ROWS) {
        // ---- LayerNorm path ----
        const int row = bid;
        const float4 v = ((const float4*)(x + (size_t)row * D_))[tid];

        float s  = v.x + v.y + v.z + v.w;
        float s2 = v.x * v.x + v.y * v.y + v.z * v.z + v.w * v.w;
        #pragma unroll
        for (int off = 32; off > 0; off >>= 1) {
            s  += __shfl_down(s,  off);
            s2 += __shfl_down(s2, off);
        }
        __shared__ float red[8];
        if ((tid & 63) == 0) { red[tid >> 6] = s; red[4 + (tid >> 6)] = s2; }
        __syncthreads();
        const float S  = red[0] + red[1] + red[2] + red[3];
        const float S2 = red[4] + red[5] + red[6] + red[7];
        const float mean = S * (1.0f / D_);
        const float var  = S2 * (1.0f / D_) - mean * mean;
        const float rstd = rsqrtf(var + EPS_);

        const float4 G1 = ((const float4*)g1)[tid];
        const float4 B1 = ((const float4*)b1)[tid];
        const float4 G2 = ((const float4*)g2)[tid];
        const float4 B2 = ((const float4*)b2)[tid];

        float nx[4] = { (v.x - mean) * rstd, (v.y - mean) * rstd,
                        (v.z - mean) * rstd, (v.w - mean) * rstd };
        ushort4 o1, o2;
        o1.x = f2bf(nx[0] * G1.x + B1.x); o1.y = f2bf(nx[1] * G1.y + B1.y);
        o1.z = f2bf(nx[2] * G1.z + B1.z); o1.w = f2bf(nx[3] * G1.w + B1.w);
        o2.x = f2bf(nx[0] * G2.x + B2.x); o2.y = f2bf(nx[1] * G2.y + B2.y);
        o2.z = f2bf(nx[2] * G2.z + B2.z); o2.w = f2bf(nx[3] * G2.w + B2.w);
        ((ushort4*)(xn + (size_t)row * D_))[tid] = o1;
        ((ushort4*)(cn + (size_t)row * D_))[tid] = o2;
    } else {
        // ---- weight transpose path: fp32 [K=1024][N] -> bf16 [N][1024] ----
        const int zz = bid - BN_ROWS;           // 0..4095
        const float* src;
        unsigned short* dst;
        int N, t;
        if (zz < 1024)      { src = Wq;  dst = wqkvT;                       N = 1024; t = zz; }
        else if (zz < 3072) { src = Wkv; dst = wqkvT + (size_t)1024 * 1024; N = 2048; t = zz - 1024; }
        else                { src = Wo;  dst = woT;                         N = 1024; t = zz - 3072; }
        const int nb = N / 32;
        const int n0 = (t % nb) * 32, k0 = (t / nb) * 32;

        __shared__ float tile[32][33];
        const int tx = tid & 31, ty = tid >> 5;   // 32 x 8
        #pragma unroll
        for (int i = 0; i < 4; i++)
            tile[ty + i * 8][tx] = src[(size_t)(k0 + ty + i * 8) * N + n0 + tx];
        __syncthreads();
        #pragma unroll
        for (int i = 0; i < 4; i++)
            dst[(size_t)(n0 + ty + i * 8) * 1024 + k0 + tx] = f2bf(tile[tx][ty + i * 8]);
    }
}

// ---------------------------------------------------------------------------
// Kernel 2: bf16 GEMM (m97 structure), templated on BM (128 or 64) and MINW
// (min waves/SIMD: occupancy floor). QKV uses MINW=3 -> 3 blocks/CU so the
// 768-block grid is FULLY resident (no 1.5x tail). LDS 32KB*3=96KB OK.
// async global->LDS (16B) staging, XOR swizzle on the GLOBAL source address
// -> conflict-free ds_read_b128. 4 waves in 2x2, each (BM/2)x64.
// FUSED (QKV): A = A0 (Q, pre-scaled 0.125*log2e) for cols<1024 else A1 (KV);
//   V region (cols>=2048) is written TRANSPOSED-TILED to vt:
//   vt[((b*32+kt)*1024 + c)*64 + key_in_tile]  (b64 packed stores).
// ---------------------------------------------------------------------------
template <int BM, bool FUSED, bool BF16OUT, int MINW>
__global__ __launch_bounds__(256, MINW) void gemm_kernel(
    const unsigned short* __restrict__ A0, const unsigned short* __restrict__ A1,
    const unsigned short* __restrict__ Bt, void* __restrict__ Cv,
    unsigned short* __restrict__ vt, int M, int N, int K) {
    constexpr int WM = BM / 2, MT = WM / 16, AI = BM / 32;
    __shared__ unsigned short As[BM * 64];
    __shared__ unsigned short Bs[128 * 64];
    const int tid = threadIdx.x, lane = tid & 63, w = tid >> 6;
    const int quad = lane >> 4, l16 = lane & 15;
    const int lr8 = lane >> 3, pg8 = lane & 7;
    const int wr = (w >> 1) * WM, wc = (w & 1) * 64;
    const int bm = blockIdx.y * BM, bn = blockIdx.x * 128;
    const unsigned short* A = (FUSED && bn >= 1024) ? A1 : A0;
    const float cscale = (FUSED && bn < 1024) ? 0.180336880111120f : 1.0f;

    f32x4_t acc[MT][4] = {};
    for (int k0 = 0; k0 < K; k0 += 64) {
        #pragma unroll
        for (int i = 0; i < AI; i++) {
            const int rb = w * (BM / 4) + i * 8;
            const int r  = rb + lr8;
            const int g  = pg8 ^ (r & 7);
            async16(&A[(size_t)(bm + r) * K + k0 + g * 8], &As[rb * 64]);
        }
        #pragma unroll
        for (int i = 0; i < 4; i++) {
            const int rb = w * 32 + i * 8;
            const int r  = rb + lr8;
            const int g  = pg8 ^ (r & 7);
            async16(&Bt[(size_t)(bn + r) * K + k0 + g * 8], &Bs[rb * 64]);
        }
        __syncthreads();
        #pragma unroll
        for (int kk = 0; kk < 64; kk += 32) {
            bf16x8_t af[MT], bfr[4];
            const int g0 = (kk >> 3) + quad;
            #pragma unroll
            for (int t = 0; t < MT; t++)
                af[t] = *(const bf16x8_t*)&As[(wr + t * 16 + l16) * 64 +
                                              ((g0 ^ (l16 & 7)) * 8)];
            #pragma unroll
            for (int t = 0; t < 4; t++)
                bfr[t] = *(const bf16x8_t*)&Bs[(wc + t * 16 + l16) * 64 +
                                               ((g0 ^ (l16 & 7)) * 8)];
            #pragma unroll
            for (int mt = 0; mt < MT; mt++)
                #pragma unroll
                for (int nt = 0; nt < 4; nt++)
                    acc[mt][nt] = MFMA32(af[mt], bfr[nt], acc[mt][nt]);
        }
        __syncthreads();
    }

    if (FUSED && bn >= 2048) {
        // V region -> tiled transpose into vt. Wave tile = 64 seq x 64 cols.
        const int seq0 = bm + wr;                 // multiple of 64
        const int bq = seq0 >> 11;                // batch
        const int kt = (seq0 & (N_ - 1)) >> 6;    // 64-key tile within batch
        #pragma unroll
        for (int nt = 0; nt < 4; nt++) {
            const int c = (bn - 2048) + wc + nt * 16 + l16;   // 0..1023
            unsigned short* dst =
                vt + (((size_t)(bq * 32 + kt) * 1024) + c) * 64;
            #pragma unroll
            for (int mt = 0; mt < 4; mt++) {
                uint2 v2 = { pk2bf(acc[mt][nt][0], acc[mt][nt][1]),
                             pk2bf(acc[mt][nt][2], acc[mt][nt][3]) };
                *(uint2*)&dst[mt * 16 + quad * 4] = v2;   // 4 consecutive keys
            }
        }
        return;
    }

    #pragma unroll
    for (int mt = 0; mt < MT; mt++)
        #pragma unroll
        for (int nt = 0; nt < 4; nt++)
            #pragma unroll
            for (int r = 0; r < 4; r++) {
                const int row = bm + wr + mt * 16 + quad * 4 + r;
                const int col = bn + wc + nt * 16 + l16;
                if (BF16OUT)
                    ((unsigned short*)Cv)[(size_t)row * N + col] =
                        f2bf(acc[mt][nt][r] * cscale);
                else
                    ((float*)Cv)[(size_t)row * N + col] = acc[mt][nt][r];
            }
}

// ---------------------------------------------------------------------------
// Kernel 3: causal flash attention. LDS-BW-focused redesign:
//   wave (kt = w&3, qth = w>>2): owns 16 UNIQUE keys x 32 queries.
//   K: per-lane GLOBAL loads straight into A-fragments (register ping-pong
//      k0r/k1r, issued one iteration ahead; L2-resident via XCD swizzle).
//   Q: per-lane global loads into B-fragments once per phase (registers).
//   V: only LDS-staged tensor (async16, triple-buffered, XOR-swizzled).
//   -> LDS traffic 80KB -> 24KB per block-iteration (was the bottleneck).
// Software pipeline kept: QK(jt) -> PV(jt-1) -> exp(jt).
// O/l partial over 4 key-groups -> 2-step LDS reduction tree per phase
// through Red (33KB). Paired (qt,31-qt) tiles: 512 blocks x 512 thr, 2/CU.
// ---------------------------------------------------------------------------
__global__ __launch_bounds__(512, 4) void flash_attn_kernel(
    const unsigned short* __restrict__ qkv, const unsigned short* __restrict__ vt,
    unsigned short* __restrict__ out) {
    __shared__ unsigned short Vts[3][64 * 64];   // [dh][key], swizzled, tribuf
    __shared__ float Red[2 * 64 * 66];           // reduction scratch (33KB)

    const int tid = threadIdx.x, lane = tid & 63, w = tid >> 6;  // w: 0..7
    const int quad = lane >> 4, l16 = lane & 15;
    const int lr8 = lane >> 3, pg8 = lane & 7;
    const int kt  = w & 3;     // key sub-tile (16 unique keys) of this wave
    const int qth = w >> 2;    // query half (32 queries)
    // XCD swizzle (8 XCDs, assume round-robin bid%8): same bh -> same XCD
    const int bid = blockIdx.x;
    const int bh   = (bid & 7) * 4 + ((bid >> 3) & 3);   // 0..31
    const int pair = bid >> 5;                           // 0..15
    const int b = bh >> 4, h = bh & 15;

    const unsigned short* qb  = qkv + (size_t)(b * N_) * QKV_N + h * DH_;
    const unsigned short* kb  = qb + 1024;
    const unsigned short* vtb = vt + ((size_t)(b * 32) * 1024 + h * 64) * 64;

    bf16x4_t ones4;
    #pragma unroll
    for (int j = 0; j < 4; j++) ones4[j] = (short)0x3F80;   // bf16 1.0

    for (int phase = 0; phase < 2; phase++) {
        const int qti = phase ? (31 - pair) : pair;  // 64-query tile index
        const int qs = qti * 64;
        const int niter = qti + 1;

        f32x4_t o[2][4] = {};       // [qtile][nt]
        f32x4_t lacc[2] = {};
        bf16x8_t qf[2][2];          // [qtile][k2], loop-invariant
        bf16x4_t pfA[2];            // carried P fragments [qtile]
        bf16x8_t k0r[2], k1r[2];    // K A-frag ping-pong [k2]

        // stage V tile t into Vts[t%3] (8 waves x 8 dh-rows, XOR-swizzled src)
        auto stageV = [&](int t) {
            const int vsel = t % 3;
            const int r = w * 8 + lr8;
            const int g = pg8 ^ (r & 7);
            async16(&vtb[((size_t)t * 1024 + r) * 64 + g * 8],
                    &Vts[vsel][(w * 8) * 64]);
        };
        // K A-fragment direct from global: row = key (l16), k = quad-chunk
        auto loadK = [&](int t, bf16x8_t (&kr)[2]) {
            #pragma unroll
            for (int k2 = 0; k2 < 2; k2++)
                kr[k2] = *(const bf16x8_t*)&kb[
                    (size_t)(t * 64 + kt * 16 + l16) * QKV_N + (k2 * 4 + quad) * 8];
        };
        // S^T = K . Q^T : m = 16 keys, n = 2x16 queries
        auto do_qk = [&](const bf16x8_t (&kr)[2], f32x4_t* s) {
            #pragma unroll
            for (int k2 = 0; k2 < 2; k2++)
                #pragma unroll
                for (int qt = 0; qt < 2; qt++)
                    s[qt] = MFMA32(kr[k2], qf[qt][k2], s[qt]);
        };
        // p = exp2(s); mask only on the diagonal tile. pf = A-frag of K=16 MFMA.
        auto do_exp = [&](const f32x4_t* s, int js, bool edge) {
            #pragma unroll
            for (int qt = 0; qt < 2; qt++) {
                float p[4];
                #pragma unroll
                for (int r = 0; r < 4; r++) {
                    float sv = s[qt][r];
                    if (edge) {
                        const int key = js + kt * 16 + quad * 4 + r;
                        const int qy  = qs + qth * 32 + qt * 16 + l16;
                        if (key > qy) sv = -3e38f;
                    }
                    p[r] = __builtin_amdgcn_exp2f(sv);
                }
                uint2 pk = { pk2bf(p[0], p[1]), pk2bf(p[2], p[3]) };
                pfA[qt] = *(bf16x4_t*)&pk;
            }
        };
        // O += P.V ; l += P.1  (bv shared across qtiles: 4 b64 reads total)
        auto do_pv = [&](int vbuf) {
            const int col = (((kt * 2 + (quad >> 1)) ^ (l16 & 7)) * 8)
                            + (quad & 1) * 4;
            #pragma unroll
            for (int nt = 0; nt < 4; nt++) {
                const bf16x4_t bv = *(const bf16x4_t*)&Vts[vbuf][
                    (nt * 16 + l16) * 64 + col];
                #pragma unroll
                for (int qt = 0; qt < 2; qt++)
                    o[qt][nt] = MFMA16(pfA[qt], bv, o[qt][nt]);
            }
            #pragma unroll
            for (int qt = 0; qt < 2; qt++)
                lacc[qt] = MFMA16(pfA[qt], ones4, lacc[qt]);
        };

        // prologue: Q B-frags (global), V(0) stage, K(0) regs
        #pragma unroll
        for (int qt = 0; qt < 2; qt++)
            #pragma unroll
            for (int k2 = 0; k2 < 2; k2++)
                qf[qt][k2] = *(const bf16x8_t*)&qb[
                    (size_t)(qs + qth * 32 + qt * 16 + l16) * QKV_N
                    + (k2 * 4 + quad) * 8];
        stageV(0);
        loadK(0, k0r);
        __syncthreads();           // V(0) DMA + K(0)/Q loads drained
        if (niter > 1) { stageV(1); loadK(1, k1r); }
        {   // peeled iteration 0: QK + exp (PV deferred)
            f32x4_t s[2] = {};
            do_qk(k0r, s);
            do_exp(s, 0, niter == 1);
        }

        for (int jt = 1; jt < niter; jt++) {
            __syncthreads();       // V(jt) DMA + K(jt) loads complete
            const bool nxt = (jt + 1 < niter);
            f32x4_t s[2] = {};
            if (jt & 1) {          // wave-uniform parity branch (rule #20:
                if (nxt) { stageV(jt + 1); loadK(jt + 1, k0r); }
                do_qk(k1r, s);     //  named K reg sets, no runtime indexing)
            } else {
                if (nxt) { stageV(jt + 1); loadK(jt + 1, k1r); }
                do_qk(k0r, s);
            }
            do_pv((jt - 1) % 3);   // previous tile PV (independent of s)
            do_exp(s, jt * 64, jt == niter - 1);
        }
        do_pv((niter - 1) % 3);    // drain the pipeline

        // 2-step reduction over the 4 key-groups (kt), via Red LDS.
        // step 1: kt odd writes; step 2: kt even adds; step 3: kt2 writes
        // pair-sum; step 4: kt0 adds + epilogue. Rows conflict-free (l16).
        if (kt & 1) {
            float* R = &Red[(kt >> 1) * 64 * 66];
            #pragma unroll
            for (int qt = 0; qt < 2; qt++)
                #pragma unroll
                for (int r = 0; r < 4; r++) {
                    const int row = qth * 32 + qt * 16 + quad * 4 + r;
                    #pragma unroll
                    for (int nt = 0; nt < 4; nt++)
                        R[row * 66 + nt * 16 + l16] = o[qt][nt][r];
                    R[row * 66 + 64] = lacc[qt][r];  // same val all l16: benign
                }
        }
        __syncthreads();
        if (!(kt & 1)) {
            float* R = &Red[(kt >> 1) * 64 * 66];
            #pragma unroll
            for (int qt = 0; qt < 2; qt++)
                #pragma unroll
                for (int r = 0; r < 4; r++) {
                    const int row = qth * 32 + qt * 16 + quad * 4 + r;
                    #pragma unroll
                    for (int nt = 0; nt < 4; nt++)
                        o[qt][nt][r] += R[row * 66 + nt * 16 + l16];
                    lacc[qt][r] += R[row * 66 + 64];
                }
        }
        __syncthreads();
        if (kt == 2) {
            float* R = &Red[0];
            #pragma unroll
            for (int qt = 0; qt < 2; qt++)
                #pragma unroll
                for (int r = 0; r < 4; r++) {
                    const int row = qth * 32 + qt * 16 + quad * 4 + r;
                    #pragma unroll
                    for (int nt = 0; nt < 4; nt++)
                        R[row * 66 + nt * 16 + l16] = o[qt][nt][r];
                    R[row * 66 + 64] = lacc[qt][r];
                }
        }
        __syncthreads();
        if (kt == 0) {
            float* R = &Red[0];
            #pragma unroll
            for (int qt = 0; qt < 2; qt++)
                #pragma unroll
                for (int r = 0; r < 4; r++) {
                    const int row = qth * 32 + qt * 16 + quad * 4 + r;
                    #pragma unroll
                    for (int nt = 0; nt < 4; nt++)
                        o[qt][nt][r] += R[row * 66 + nt * 16 + l16];
                    const float inv = 1.0f / (lacc[qt][r] + R[row * 66 + 64]);
                    const int query = qs + row;
                    const int orow  = b * N_ + query;
                    #pragma unroll
                    for (int nt = 0; nt < 4; nt++) {
                        const int col = h * DH_ + nt * 16 + l16;
                        out[(size_t)orow * (H_ * DH_) + col] =
                            f2bf(o[qt][nt][r] * inv);
                    }
                }
        }
        // next phase's first __syncthreads() (after stageV(0)) protects Red:
        // phase-1 reduction writes happen only after its full K-loop.
    }
}

// ---------------------------------------------------------------------------
// Host launcher
// ---------------------------------------------------------------------------
extern "C" void kernel_launch(void* const* d_in, const int* in_sizes, int n_in,
                              void* d_out, int out_size, void* d_ws, size_t ws_size,
                              hipStream_t stream) {
    const float* x     = (const float*)d_in[0];
    const float* ln_g  = (const float*)d_in[1];
    const float* ln_b  = (const float*)d_in[2];
    const float* lnc_g = (const float*)d_in[3];
    const float* lnc_b = (const float*)d_in[4];
    const float* Wq    = (const float*)d_in[5];
    const float* Wkv   = (const float*)d_in[6];
    const float* Wo    = (const float*)d_in[7];

    char* ws = (char*)d_ws;
    const size_t MB = 1024 * 1024;
    unsigned short* qkv   = (unsigned short*)(ws + 0 * MB);    // [4096][3072] 24 MB (V region unused)
    unsigned short* vtbuf = (unsigned short*)(ws + 24 * MB);   // tiled V^T      8 MB
    unsigned short* xn    = (unsigned short*)(ws + 32 * MB);   // [4096][1024]  8 MB
    unsigned short* cn    = (unsigned short*)(ws + 40 * MB);   // [4096][1024]  8 MB
    unsigned short* wqkvT = (unsigned short*)(ws + 48 * MB);   // [3072][1024]  6 MB
    unsigned short* woT   = (unsigned short*)(ws + 54 * MB);   // [1024][1024]  2 MB
    unsigned short* ao    = xn;   // reuse: xn dead after QKV GEMM

    // LN (blocks 0..4095) + weight transposes (blocks 4096..8191), one dispatch
    ln_wt_kernel<<<8192, 256, 0, stream>>>(
        x, ln_g, ln_b, lnc_g, lnc_b, Wq, Wkv, Wo, xn, cn, wqkvT, woT);

    // fused Q+KV GEMM; Q pre-scaled; V written tiled-transposed to vtbuf
    // MINW=3: 768 blocks fully resident (3/CU), no occupancy tail
    gemm_kernel<128, true, true, 3>
        <<<dim3(QKV_N / 128, BN_ROWS / 128), 256, 0, stream>>>(
        xn, cn, wqkvT, qkv, vtbuf, BN_ROWS, QKV_N, D_);

    // paired 64-query tiles (qt, 31-qt): 512 blocks x 512 threads, 2/CU
    flash_attn_kernel<<<B_ * H_ * 16, 512, 0, stream>>>(qkv, vtbuf, ao);

    // out = ao @ woT^T (fp32 out); BM=64 -> 512 blocks = 2/CU
    gemm_kernel<64, false, false, 2>
        <<<dim3(D_ / 128, BN_ROWS / 64), 256, 0, stream>>>(
        ao, nullptr, woT, (float*)d_out, nullptr, BN_ROWS, D_, H_ * DH_);
}

// Round 8
// 184.365 us; speedup vs baseline: 1.0713x; 1.0713x over previous
//
#include <hip/hip_runtime.h>
#include <hip/hip_bf16.h>

// ---------------------------------------------------------------------------
// Problem constants
// ---------------------------------------------------------------------------
#define B_  2
#define N_  2048
#define D_  1024
#define H_  16
#define DH_ 64
#define BN_ROWS (B_ * N_)   // 4096
#define EPS_ 1e-5f
#define QKV_N 3072          // fused [Q | K | V] output width

typedef __attribute__((ext_vector_type(8))) short bf16x8_t;
typedef __attribute__((ext_vector_type(4))) short bf16x4_t;
typedef __attribute__((ext_vector_type(4))) float f32x4_t;

// K=16 bf16 MFMA (v_mfma_f32_16x16x16_bf16): A/B = 4 bf16 (k = quad*4+reg),
// C/D = 4 f32 (row = quad*4+r, col = l16).
#define MFMA16(a, b, c) __builtin_amdgcn_mfma_f32_16x16x16bf16_1k(a, b, c, 0, 0, 0)
#define MFMA32(a, b, c) __builtin_amdgcn_mfma_f32_16x16x32_bf16(a, b, c, 0, 0, 0)

typedef const unsigned int __attribute__((address_space(1)))* gas_ptr;
typedef unsigned int __attribute__((address_space(3)))* las_ptr;

// async global->LDS, 16B per lane, dest = wave-uniform base + lane*16
__device__ __forceinline__ void async16(const unsigned short* g, unsigned short* l) {
    __builtin_amdgcn_global_load_lds((gas_ptr)g, (las_ptr)l, 16, 0, 0);
}

__device__ __forceinline__ unsigned short f2bf(float f) {
    unsigned int u = __float_as_uint(f);
    unsigned int r = u + 0x7FFFu + ((u >> 16) & 1u);   // round-to-nearest-even
    return (unsigned short)(r >> 16);
}

// pack two f32 -> bf16x2
__device__ __forceinline__ unsigned int pk2bf(float a, float b) {
    __hip_bfloat162 t = __float22bfloat162_rn(float2{a, b});
    return *(unsigned int*)&t;
}

// ---------------------------------------------------------------------------
// Kernel 1: fused dual LayerNorm + all-weight bf16 transposes (one dispatch).
// blocks [0,4096): LN rows. blocks [4096,8192): weight transpose tiles.
// ---------------------------------------------------------------------------
__global__ __launch_bounds__(256) void ln_wt_kernel(
    const float* __restrict__ x,
    const float* __restrict__ g1, const float* __restrict__ b1,
    const float* __restrict__ g2, const float* __restrict__ b2,
    const float* __restrict__ Wq, const float* __restrict__ Wkv,
    const float* __restrict__ Wo,
    unsigned short* __restrict__ xn, unsigned short* __restrict__ cn,
    unsigned short* __restrict__ wqkvT, unsigned short* __restrict__ woT) {
    const int bid = blockIdx.x;
    const int tid = threadIdx.x;

    if (bid < BN_ROWS) {
        // ---- LayerNorm path ----
        const int row = bid;
        const float4 v = ((const float4*)(x + (size_t)row * D_))[tid];

        float s  = v.x + v.y + v.z + v.w;
        float s2 = v.x * v.x + v.y * v.y + v.z * v.z + v.w * v.w;
        #pragma unroll
        for (int off = 32; off > 0; off >>= 1) {
            s  += __shfl_down(s,  off);
            s2 += __shfl_down(s2, off);
        }
        __shared__ float red[8];
        if ((tid & 63) == 0) { red[tid >> 6] = s; red[4 + (tid >> 6)] = s2; }
        __syncthreads();
        const float S  = red[0] + red[1] + red[2] + red[3];
        const float S2 = red[4] + red[5] + red[6] + red[7];
        const float mean = S * (1.0f / D_);
        const float var  = S2 * (1.0f / D_) - mean * mean;
        const float rstd = rsqrtf(var + EPS_);

        const float4 G1 = ((const float4*)g1)[tid];
        const float4 B1 = ((const float4*)b1)[tid];
        const float4 G2 = ((const float4*)g2)[tid];
        const float4 B2 = ((const float4*)b2)[tid];

        float nx[4] = { (v.x - mean) * rstd, (v.y - mean) * rstd,
                        (v.z - mean) * rstd, (v.w - mean) * rstd };
        ushort4 o1, o2;
        o1.x = f2bf(nx[0] * G1.x + B1.x); o1.y = f2bf(nx[1] * G1.y + B1.y);
        o1.z = f2bf(nx[2] * G1.z + B1.z); o1.w = f2bf(nx[3] * G1.w + B1.w);
        o2.x = f2bf(nx[0] * G2.x + B2.x); o2.y = f2bf(nx[1] * G2.y + B2.y);
        o2.z = f2bf(nx[2] * G2.z + B2.z); o2.w = f2bf(nx[3] * G2.w + B2.w);
        ((ushort4*)(xn + (size_t)row * D_))[tid] = o1;
        ((ushort4*)(cn + (size_t)row * D_))[tid] = o2;
    } else {
        // ---- weight transpose path: fp32 [K=1024][N] -> bf16 [N][1024] ----
        const int zz = bid - BN_ROWS;           // 0..4095
        const float* src;
        unsigned short* dst;
        int N, t;
        if (zz < 1024)      { src = Wq;  dst = wqkvT;                       N = 1024; t = zz; }
        else if (zz < 3072) { src = Wkv; dst = wqkvT + (size_t)1024 * 1024; N = 2048; t = zz - 1024; }
        else                { src = Wo;  dst = woT;                         N = 1024; t = zz - 3072; }
        const int nb = N / 32;
        const int n0 = (t % nb) * 32, k0 = (t / nb) * 32;

        __shared__ float tile[32][33];
        const int tx = tid & 31, ty = tid >> 5;   // 32 x 8
        #pragma unroll
        for (int i = 0; i < 4; i++)
            tile[ty + i * 8][tx] = src[(size_t)(k0 + ty + i * 8) * N + n0 + tx];
        __syncthreads();
        #pragma unroll
        for (int i = 0; i < 4; i++)
            dst[(size_t)(n0 + ty + i * 8) * 1024 + k0 + tx] = f2bf(tile[tx][ty + i * 8]);
    }
}

// ---------------------------------------------------------------------------
// Kernel 2: bf16 GEMM (m97 structure), templated on BM (128 or 64) and MINW
// (min waves/SIMD: occupancy floor). QKV uses MINW=3 -> 3 blocks/CU so the
// 768-block grid is FULLY resident (no 1.5x tail). LDS 32KB*3=96KB OK.
// async global->LDS (16B) staging, XOR swizzle on the GLOBAL source address
// -> conflict-free ds_read_b128. 4 waves in 2x2, each (BM/2)x64.
// FUSED (QKV): A = A0 (Q, pre-scaled 0.125*log2e) for cols<1024 else A1 (KV);
//   V region (cols>=2048) is written TRANSPOSED-TILED to vt:
//   vt[((b*32+kt)*1024 + c)*64 + key_in_tile]  (b64 packed stores).
// ---------------------------------------------------------------------------
template <int BM, bool FUSED, bool BF16OUT, int MINW>
__global__ __launch_bounds__(256, MINW) void gemm_kernel(
    const unsigned short* __restrict__ A0, const unsigned short* __restrict__ A1,
    const unsigned short* __restrict__ Bt, void* __restrict__ Cv,
    unsigned short* __restrict__ vt, int M, int N, int K) {
    constexpr int WM = BM / 2, MT = WM / 16, AI = BM / 32;
    __shared__ unsigned short As[BM * 64];
    __shared__ unsigned short Bs[128 * 64];
    const int tid = threadIdx.x, lane = tid & 63, w = tid >> 6;
    const int quad = lane >> 4, l16 = lane & 15;
    const int lr8 = lane >> 3, pg8 = lane & 7;
    const int wr = (w >> 1) * WM, wc = (w & 1) * 64;
    const int bm = blockIdx.y * BM, bn = blockIdx.x * 128;
    const unsigned short* A = (FUSED && bn >= 1024) ? A1 : A0;
    const float cscale = (FUSED && bn < 1024) ? 0.180336880111120f : 1.0f;

    f32x4_t acc[MT][4] = {};
    for (int k0 = 0; k0 < K; k0 += 64) {
        #pragma unroll
        for (int i = 0; i < AI; i++) {
            const int rb = w * (BM / 4) + i * 8;
            const int r  = rb + lr8;
            const int g  = pg8 ^ (r & 7);
            async16(&A[(size_t)(bm + r) * K + k0 + g * 8], &As[rb * 64]);
        }
        #pragma unroll
        for (int i = 0; i < 4; i++) {
            const int rb = w * 32 + i * 8;
            const int r  = rb + lr8;
            const int g  = pg8 ^ (r & 7);
            async16(&Bt[(size_t)(bn + r) * K + k0 + g * 8], &Bs[rb * 64]);
        }
        __syncthreads();
        #pragma unroll
        for (int kk = 0; kk < 64; kk += 32) {
            bf16x8_t af[MT], bfr[4];
            const int g0 = (kk >> 3) + quad;
            #pragma unroll
            for (int t = 0; t < MT; t++)
                af[t] = *(const bf16x8_t*)&As[(wr + t * 16 + l16) * 64 +
                                              ((g0 ^ (l16 & 7)) * 8)];
            #pragma unroll
            for (int t = 0; t < 4; t++)
                bfr[t] = *(const bf16x8_t*)&Bs[(wc + t * 16 + l16) * 64 +
                                               ((g0 ^ (l16 & 7)) * 8)];
            #pragma unroll
            for (int mt = 0; mt < MT; mt++)
                #pragma unroll
                for (int nt = 0; nt < 4; nt++)
                    acc[mt][nt] = MFMA32(af[mt], bfr[nt], acc[mt][nt]);
        }
        __syncthreads();
    }

    if (FUSED && bn >= 2048) {
        // V region -> tiled transpose into vt. Wave tile = 64 seq x 64 cols.
        const int seq0 = bm + wr;                 // multiple of 64
        const int bq = seq0 >> 11;                // batch
        const int kt = (seq0 & (N_ - 1)) >> 6;    // 64-key tile within batch
        #pragma unroll
        for (int nt = 0; nt < 4; nt++) {
            const int c = (bn - 2048) + wc + nt * 16 + l16;   // 0..1023
            unsigned short* dst =
                vt + (((size_t)(bq * 32 + kt) * 1024) + c) * 64;
            #pragma unroll
            for (int mt = 0; mt < 4; mt++) {
                uint2 v2 = { pk2bf(acc[mt][nt][0], acc[mt][nt][1]),
                             pk2bf(acc[mt][nt][2], acc[mt][nt][3]) };
                *(uint2*)&dst[mt * 16 + quad * 4] = v2;   // 4 consecutive keys
            }
        }
        return;
    }

    #pragma unroll
    for (int mt = 0; mt < MT; mt++)
        #pragma unroll
        for (int nt = 0; nt < 4; nt++)
            #pragma unroll
            for (int r = 0; r < 4; r++) {
                const int row = bm + wr + mt * 16 + quad * 4 + r;
                const int col = bn + wc + nt * 16 + l16;
                if (BF16OUT)
                    ((unsigned short*)Cv)[(size_t)row * N + col] =
                        f2bf(acc[mt][nt][r] * cscale);
                else
                    ((float*)Cv)[(size_t)row * N + col] = acc[mt][nt][r];
            }
}

// ---------------------------------------------------------------------------
// Kernel 3: causal flash attention, S^T scheme, software-pipelined
// (QK(jt) -> PV(jt-1) -> exp(jt)), 8 WAVES / 512 THREADS per block:
// key dimension split across wave halves (wk = w>>2): waves w and w+4 share
// the same 16 queries (wq = w&3), each handles 2 of 4 key sub-tiles.
// -> 4 waves/SIMD (vs 2) to fill the lgkm/barrier stalls; per-wave work
// halves; one cross-wave O/l reduction per phase through the dead Vts LDS.
// V triple-buffered; K double-buffered. exp via raw v_exp_f32.
// XCD-aware swizzle; paired (qt, 31-qt) tiles: 512 blocks = 2/CU, balanced.
// (Round-6 version, re-instated: R7's global-K variant doubled HBM traffic
//  and regressed 39->56 us.)
// ---------------------------------------------------------------------------
__global__ __launch_bounds__(512, 4) void flash_attn_kernel(
    const unsigned short* __restrict__ qkv, const unsigned short* __restrict__ vt,
    unsigned short* __restrict__ out) {
    __shared__ unsigned short Qs[64 * 64];       // [query][dh], swizzled
    __shared__ unsigned short Ks[2][64 * 64];    // [key][dh], swizzled, dbuf
    __shared__ unsigned short Vts[3][64 * 64];   // [dh][key], swizzled, tribuf

    const int tid = threadIdx.x, lane = tid & 63, w = tid >> 6;  // w: 0..7
    const int quad = lane >> 4, l16 = lane & 15;
    const int lr8 = lane >> 3, pg8 = lane & 7;
    const int wq = w & 3;       // query sub-tile (16 rows)
    const int wk = w >> 2;      // key half (0: keys 0-31, 1: keys 32-63)
    // XCD swizzle (8 XCDs, assume round-robin bid%8): same bh -> same XCD
    const int bid = blockIdx.x;
    const int bh   = (bid & 7) * 4 + ((bid >> 3) & 3);   // 0..31
    const int pair = bid >> 5;                           // 0..15
    const int b = bh >> 4, h = bh & 15;

    const unsigned short* qb  = qkv + (size_t)(b * N_) * QKV_N + h * DH_;
    const unsigned short* kb  = qb + 1024;
    const unsigned short* vtb = vt + ((size_t)(b * 32) * 1024 + h * 64) * 64;

    bf16x4_t ones4;
    #pragma unroll
    for (int j = 0; j < 4; j++) ones4[j] = (short)0x3F80;   // bf16 1.0

    for (int phase = 0; phase < 2; phase++) {
        const int qt = phase ? (31 - pair) : pair;   // 64-query tile index
        const int qs = qt * 64;
        const int niter = qt + 1;

        __syncthreads();   // previous phase fully done with Qs/Ks/Vts (incl red)

        f32x4_t o[4] = {};
        f32x4_t lacc = {};
        bf16x8_t qf[2];
        bf16x4_t pf[2];    // pipelined P fragments (this wave's 2 key tiles)

        // stage tile t into K[t&1], V[t%3]: 8 waves x 8 rows each
        auto prefetch = [&](int t) {
            const int ksel = t & 1, vsel = t % 3;
            const int rb = w * 8;
            const int r  = rb + lr8;
            const int g  = pg8 ^ (r & 7);
            async16(&kb[(size_t)(t * 64 + r) * QKV_N + g * 8], &Ks[ksel][rb * 64]);
            async16(&vtb[((size_t)t * 1024 + r) * 64 + g * 8], &Vts[vsel][rb * 64]);
        };
        // S^T = K . Q^T : m = this wave's 32 keys (2 kt), n = 16 queries
        auto do_qk = [&](int kbuf, f32x4_t* s) {
            #pragma unroll
            for (int k2 = 0; k2 < 2; k2++) {
                const int g0 = k2 * 4 + quad;
                #pragma unroll
                for (int kt = 0; kt < 2; kt++) {
                    const int ktg = wk * 2 + kt;
                    const bf16x8_t a = *(const bf16x8_t*)&Ks[kbuf][
                        (ktg * 16 + l16) * 64 + (g0 ^ (l16 & 7)) * 8];
                    s[kt] = MFMA32(a, qf[k2], s[kt]);
                }
            }
        };
        // p = exp2(s); mask only on the diagonal tile. pf = A-frag of K=16 MFMA.
        auto do_exp = [&](const f32x4_t* s, int js, bool edge) {
            #pragma unroll
            for (int kt = 0; kt < 2; kt++) {
                const int ktg = wk * 2 + kt;
                float p[4];
                #pragma unroll
                for (int r = 0; r < 4; r++) {
                    float sv = s[kt][r];
                    if (edge) {
                        const int key = js + ktg * 16 + quad * 4 + r;
                        const int qy  = qs + wq * 16 + l16;
                        if (key > qy) sv = -3e38f;
                    }
                    p[r] = __builtin_amdgcn_exp2f(sv);
                }
                uint2 pk = { pk2bf(p[0], p[1]), pk2bf(p[2], p[3]) };
                pf[kt] = *(bf16x4_t*)&pk;
            }
        };
        // O += P.V ; l += P.1  (in-register A, K=16 MFMAs; partial over wk)
        auto do_pv = [&](int vbuf) {
            #pragma unroll
            for (int kt = 0; kt < 2; kt++) {
                const int ktg = wk * 2 + kt;
                const int g = ktg * 2 + (quad >> 1);
                const int col = ((g ^ (l16 & 7)) * 8) + (quad & 1) * 4;
                #pragma unroll
                for (int nt = 0; nt < 4; nt++) {
                    const bf16x4_t bv = *(const bf16x4_t*)&Vts[vbuf][
                        (nt * 16 + l16) * 64 + col];
                    o[nt] = MFMA16(pf[kt], bv, o[nt]);
                }
                lacc = MFMA16(pf[kt], ones4, lacc);
            }
        };

        // stage Q + tile 0
        {
            const int rb = w * 8;
            const int r  = rb + lr8;
            const int g  = pg8 ^ (r & 7);
            async16(&qb[(size_t)(qs + r) * QKV_N + g * 8], &Qs[rb * 64]);
        }
        prefetch(0);
        __syncthreads();           // drain Q + tile 0

        if (niter > 1) prefetch(1);
        #pragma unroll
        for (int k2 = 0; k2 < 2; k2++) {
            const int g0 = k2 * 4 + quad;
            qf[k2] = *(const bf16x8_t*)&Qs[
                (wq * 16 + l16) * 64 + (g0 ^ (l16 & 7)) * 8];
        }
        {   // peeled iteration 0: QK + exp (PV deferred)
            f32x4_t s[2] = {};
            do_qk(0, s);
            do_exp(s, 0, niter == 1);
        }

        for (int jt = 1; jt < niter; jt++) {
            __syncthreads();       // drains prefetch(jt); prior reads done
            if (jt + 1 < niter) prefetch(jt + 1);
            f32x4_t s[2] = {};
            do_qk(jt & 1, s);      // current tile scores
            do_pv((jt - 1) % 3);   // previous tile PV (independent of s)
            do_exp(s, jt * 64, jt == niter - 1);
        }
        do_pv((niter - 1) % 3);    // drain the pipeline

        // cross-wave reduction: high key-half adds into low key-half, via the
        // now-dead Vts LDS (4*16*68*4B = 17.4 KB <= 24 KB).
        __syncthreads();           // all V reads done
        float* red = (float*)&Vts[0][0];
        if (wk == 1) {
            #pragma unroll
            for (int r = 0; r < 4; r++) {
                const int q = quad * 4 + r;
                const int base = (wq * 16 + q) * 68;
                #pragma unroll
                for (int nt = 0; nt < 4; nt++)
                    red[base + nt * 16 + l16] = o[nt][r];
                red[base + 64] = lacc[r];   // same value across l16: benign race
            }
        }
        __syncthreads();
        if (wk == 0) {
            #pragma unroll
            for (int r = 0; r < 4; r++) {
                const int q = quad * 4 + r;
                const int base = (wq * 16 + q) * 68;
                #pragma unroll
                for (int nt = 0; nt < 4; nt++)
                    o[nt][r] += red[base + nt * 16 + l16];
                const float inv = 1.0f / (lacc[r] + red[base + 64]);
                const int query = qs + wq * 16 + quad * 4 + r;
                const int row = b * N_ + query;
                #pragma unroll
                for (int nt = 0; nt < 4; nt++) {
                    const int col = h * DH_ + nt * 16 + l16;
                    out[(size_t)row * (H_ * DH_) + col] = f2bf(o[nt][r] * inv);
                }
            }
        }
        // next phase's leading __syncthreads() protects red before restaging
    }
}

// ---------------------------------------------------------------------------
// Host launcher
// ---------------------------------------------------------------------------
extern "C" void kernel_launch(void* const* d_in, const int* in_sizes, int n_in,
                              void* d_out, int out_size, void* d_ws, size_t ws_size,
                              hipStream_t stream) {
    const float* x     = (const float*)d_in[0];
    const float* ln_g  = (const float*)d_in[1];
    const float* ln_b  = (const float*)d_in[2];
    const float* lnc_g = (const float*)d_in[3];
    const float* lnc_b = (const float*)d_in[4];
    const float* Wq    = (const float*)d_in[5];
    const float* Wkv   = (const float*)d_in[6];
    const float* Wo    = (const float*)d_in[7];

    char* ws = (char*)d_ws;
    const size_t MB = 1024 * 1024;
    unsigned short* qkv   = (unsigned short*)(ws + 0 * MB);    // [4096][3072] 24 MB (V region unused)
    unsigned short* vtbuf = (unsigned short*)(ws + 24 * MB);   // tiled V^T      8 MB
    unsigned short* xn    = (unsigned short*)(ws + 32 * MB);   // [4096][1024]  8 MB
    unsigned short* cn    = (unsigned short*)(ws + 40 * MB);   // [4096][1024]  8 MB
    unsigned short* wqkvT = (unsigned short*)(ws + 48 * MB);   // [3072][1024]  6 MB
    unsigned short* woT   = (unsigned short*)(ws + 54 * MB);   // [1024][1024]  2 MB
    unsigned short* ao    = xn;   // reuse: xn dead after QKV GEMM

    // LN (blocks 0..4095) + weight transposes (blocks 4096..8191), one dispatch
    ln_wt_kernel<<<8192, 256, 0, stream>>>(
        x, ln_g, ln_b, lnc_g, lnc_b, Wq, Wkv, Wo, xn, cn, wqkvT, woT);

    // fused Q+KV GEMM; Q pre-scaled; V written tiled-transposed to vtbuf
    // MINW=3: 768 blocks fully resident (3/CU), no occupancy tail
    gemm_kernel<128, true, true, 3>
        <<<dim3(QKV_N / 128, BN_ROWS / 128), 256, 0, stream>>>(
        xn, cn, wqkvT, qkv, vtbuf, BN_ROWS, QKV_N, D_);

    // paired 64-query tiles (qt, 31-qt): 512 blocks x 512 threads, 2/CU
    flash_attn_kernel<<<B_ * H_ * 16, 512, 0, stream>>>(qkv, vtbuf, ao);

    // out = ao @ woT^T (fp32 out); BM=128 (912-TF ladder tile, vs 343 TF at
    // BM=64): grid (8,32) = 256 blocks, fully resident
    gemm_kernel<128, false, false, 2>
        <<<dim3(D_ / 128, BN_ROWS / 128), 256, 0, stream>>>(
        ao, nullptr, woT, (float*)d_out, nullptr, BN_ROWS, D_, H_ * DH_);
}

// Round 9
// 182.348 us; speedup vs baseline: 1.0831x; 1.0111x over previous
//
#include <hip/hip_runtime.h>
#include <hip/hip_bf16.h>

// ---------------------------------------------------------------------------
// Problem constants
// ---------------------------------------------------------------------------
#define B_  2
#define N_  2048
#define D_  1024
#define H_  16
#define DH_ 64
#define BN_ROWS (B_ * N_)   // 4096
#define EPS_ 1e-5f
#define QKV_N 3072          // fused [Q | K | V] output width

typedef __attribute__((ext_vector_type(8))) short bf16x8_t;
typedef __attribute__((ext_vector_type(4))) short bf16x4_t;
typedef __attribute__((ext_vector_type(4))) float f32x4_t;

// K=16 bf16 MFMA (v_mfma_f32_16x16x16_bf16): A/B = 4 bf16 (k = quad*4+reg),
// C/D = 4 f32 (row = quad*4+r, col = l16).
#define MFMA16(a, b, c) __builtin_amdgcn_mfma_f32_16x16x16bf16_1k(a, b, c, 0, 0, 0)
#define MFMA32(a, b, c) __builtin_amdgcn_mfma_f32_16x16x32_bf16(a, b, c, 0, 0, 0)

typedef const unsigned int __attribute__((address_space(1)))* gas_ptr;
typedef unsigned int __attribute__((address_space(3)))* las_ptr;

// async global->LDS, 16B per lane, dest = wave-uniform base + lane*16
__device__ __forceinline__ void async16(const unsigned short* g, unsigned short* l) {
    __builtin_amdgcn_global_load_lds((gas_ptr)g, (las_ptr)l, 16, 0, 0);
}

__device__ __forceinline__ unsigned short f2bf(float f) {
    unsigned int u = __float_as_uint(f);
    unsigned int r = u + 0x7FFFu + ((u >> 16) & 1u);   // round-to-nearest-even
    return (unsigned short)(r >> 16);
}

// pack two f32 -> bf16x2
__device__ __forceinline__ unsigned int pk2bf(float a, float b) {
    __hip_bfloat162 t = __float22bfloat162_rn(float2{a, b});
    return *(unsigned int*)&t;
}

// counted-vmcnt barrier (T4): wait until at most N own VMEM ops outstanding
// (completes all older ones) + all LDS ops, then workgroup barrier. The
// "memory" clobber pins LDS/global accesses on their side of the barrier.
#define WAITBAR(N) asm volatile("s_waitcnt vmcnt(" #N ") lgkmcnt(0)\n\ts_barrier" ::: "memory")

// ---------------------------------------------------------------------------
// Kernel 1: fused dual LayerNorm + all-weight bf16 transposes (one dispatch).
// blocks [0,4096): LN rows. blocks [4096,8192): weight transpose tiles.
// ---------------------------------------------------------------------------
__global__ __launch_bounds__(256) void ln_wt_kernel(
    const float* __restrict__ x,
    const float* __restrict__ g1, const float* __restrict__ b1,
    const float* __restrict__ g2, const float* __restrict__ b2,
    const float* __restrict__ Wq, const float* __restrict__ Wkv,
    const float* __restrict__ Wo,
    unsigned short* __restrict__ xn, unsigned short* __restrict__ cn,
    unsigned short* __restrict__ wqkvT, unsigned short* __restrict__ woT) {
    const int bid = blockIdx.x;
    const int tid = threadIdx.x;

    if (bid < BN_ROWS) {
        // ---- LayerNorm path ----
        const int row = bid;
        const float4 v = ((const float4*)(x + (size_t)row * D_))[tid];

        float s  = v.x + v.y + v.z + v.w;
        float s2 = v.x * v.x + v.y * v.y + v.z * v.z + v.w * v.w;
        #pragma unroll
        for (int off = 32; off > 0; off >>= 1) {
            s  += __shfl_down(s,  off);
            s2 += __shfl_down(s2, off);
        }
        __shared__ float red[8];
        if ((tid & 63) == 0) { red[tid >> 6] = s; red[4 + (tid >> 6)] = s2; }
        __syncthreads();
        const float S  = red[0] + red[1] + red[2] + red[3];
        const float S2 = red[4] + red[5] + red[6] + red[7];
        const float mean = S * (1.0f / D_);
        const float var  = S2 * (1.0f / D_) - mean * mean;
        const float rstd = rsqrtf(var + EPS_);

        const float4 G1 = ((const float4*)g1)[tid];
        const float4 B1 = ((const float4*)b1)[tid];
        const float4 G2 = ((const float4*)g2)[tid];
        const float4 B2 = ((const float4*)b2)[tid];

        float nx[4] = { (v.x - mean) * rstd, (v.y - mean) * rstd,
                        (v.z - mean) * rstd, (v.w - mean) * rstd };
        ushort4 o1, o2;
        o1.x = f2bf(nx[0] * G1.x + B1.x); o1.y = f2bf(nx[1] * G1.y + B1.y);
        o1.z = f2bf(nx[2] * G1.z + B1.z); o1.w = f2bf(nx[3] * G1.w + B1.w);
        o2.x = f2bf(nx[0] * G2.x + B2.x); o2.y = f2bf(nx[1] * G2.y + B2.y);
        o2.z = f2bf(nx[2] * G2.z + B2.z); o2.w = f2bf(nx[3] * G2.w + B2.w);
        ((ushort4*)(xn + (size_t)row * D_))[tid] = o1;
        ((ushort4*)(cn + (size_t)row * D_))[tid] = o2;
    } else {
        // ---- weight transpose path: fp32 [K=1024][N] -> bf16 [N][1024] ----
        const int zz = bid - BN_ROWS;           // 0..4095
        const float* src;
        unsigned short* dst;
        int N, t;
        if (zz < 1024)      { src = Wq;  dst = wqkvT;                       N = 1024; t = zz; }
        else if (zz < 3072) { src = Wkv; dst = wqkvT + (size_t)1024 * 1024; N = 2048; t = zz - 1024; }
        else                { src = Wo;  dst = woT;                         N = 1024; t = zz - 3072; }
        const int nb = N / 32;
        const int n0 = (t % nb) * 32, k0 = (t / nb) * 32;

        __shared__ float tile[32][33];
        const int tx = tid & 31, ty = tid >> 5;   // 32 x 8
        #pragma unroll
        for (int i = 0; i < 4; i++)
            tile[ty + i * 8][tx] = src[(size_t)(k0 + ty + i * 8) * N + n0 + tx];
        __syncthreads();
        #pragma unroll
        for (int i = 0; i < 4; i++)
            dst[(size_t)(n0 + ty + i * 8) * 1024 + k0 + tx] = f2bf(tile[tx][ty + i * 8]);
    }
}

// ---------------------------------------------------------------------------
// Kernel 2: bf16 GEMM (m97 structure), templated on BM (128 or 64) and MINW
// (min waves/SIMD: occupancy floor). QKV uses MINW=3 -> 3 blocks/CU so the
// 768-block grid is FULLY resident (no 1.5x tail). LDS 32KB*3=96KB OK.
// async global->LDS (16B) staging, XOR swizzle on the GLOBAL source address
// -> conflict-free ds_read_b128. 4 waves in 2x2, each (BM/2)x64.
// FUSED (QKV): A = A0 (Q, pre-scaled 0.125*log2e) for cols<1024 else A1 (KV);
//   V region (cols>=2048) is written TRANSPOSED-TILED to vt:
//   vt[((b*32+kt)*1024 + c)*64 + key_in_tile]  (b64 packed stores).
// ---------------------------------------------------------------------------
template <int BM, bool FUSED, bool BF16OUT, int MINW>
__global__ __launch_bounds__(256, MINW) void gemm_kernel(
    const unsigned short* __restrict__ A0, const unsigned short* __restrict__ A1,
    const unsigned short* __restrict__ Bt, void* __restrict__ Cv,
    unsigned short* __restrict__ vt, int M, int N, int K) {
    constexpr int WM = BM / 2, MT = WM / 16, AI = BM / 32;
    __shared__ unsigned short As[BM * 64];
    __shared__ unsigned short Bs[128 * 64];
    const int tid = threadIdx.x, lane = tid & 63, w = tid >> 6;
    const int quad = lane >> 4, l16 = lane & 15;
    const int lr8 = lane >> 3, pg8 = lane & 7;
    const int wr = (w >> 1) * WM, wc = (w & 1) * 64;
    const int bm = blockIdx.y * BM, bn = blockIdx.x * 128;
    const unsigned short* A = (FUSED && bn >= 1024) ? A1 : A0;
    const float cscale = (FUSED && bn < 1024) ? 0.180336880111120f : 1.0f;

    f32x4_t acc[MT][4] = {};
    for (int k0 = 0; k0 < K; k0 += 64) {
        #pragma unroll
        for (int i = 0; i < AI; i++) {
            const int rb = w * (BM / 4) + i * 8;
            const int r  = rb + lr8;
            const int g  = pg8 ^ (r & 7);
            async16(&A[(size_t)(bm + r) * K + k0 + g * 8], &As[rb * 64]);
        }
        #pragma unroll
        for (int i = 0; i < 4; i++) {
            const int rb = w * 32 + i * 8;
            const int r  = rb + lr8;
            const int g  = pg8 ^ (r & 7);
            async16(&Bt[(size_t)(bn + r) * K + k0 + g * 8], &Bs[rb * 64]);
        }
        __syncthreads();
        #pragma unroll
        for (int kk = 0; kk < 64; kk += 32) {
            bf16x8_t af[MT], bfr[4];
            const int g0 = (kk >> 3) + quad;
            #pragma unroll
            for (int t = 0; t < MT; t++)
                af[t] = *(const bf16x8_t*)&As[(wr + t * 16 + l16) * 64 +
                                              ((g0 ^ (l16 & 7)) * 8)];
            #pragma unroll
            for (int t = 0; t < 4; t++)
                bfr[t] = *(const bf16x8_t*)&Bs[(wc + t * 16 + l16) * 64 +
                                               ((g0 ^ (l16 & 7)) * 8)];
            #pragma unroll
            for (int mt = 0; mt < MT; mt++)
                #pragma unroll
                for (int nt = 0; nt < 4; nt++)
                    acc[mt][nt] = MFMA32(af[mt], bfr[nt], acc[mt][nt]);
        }
        __syncthreads();
    }

    if (FUSED && bn >= 2048) {
        // V region -> tiled transpose into vt. Wave tile = 64 seq x 64 cols.
        const int seq0 = bm + wr;                 // multiple of 64
        const int bq = seq0 >> 11;                // batch
        const int kt = (seq0 & (N_ - 1)) >> 6;    // 64-key tile within batch
        #pragma unroll
        for (int nt = 0; nt < 4; nt++) {
            const int c = (bn - 2048) + wc + nt * 16 + l16;   // 0..1023
            unsigned short* dst =
                vt + (((size_t)(bq * 32 + kt) * 1024) + c) * 64;
            #pragma unroll
            for (int mt = 0; mt < 4; mt++) {
                uint2 v2 = { pk2bf(acc[mt][nt][0], acc[mt][nt][1]),
                             pk2bf(acc[mt][nt][2], acc[mt][nt][3]) };
                *(uint2*)&dst[mt * 16 + quad * 4] = v2;   // 4 consecutive keys
            }
        }
        return;
    }

    #pragma unroll
    for (int mt = 0; mt < MT; mt++)
        #pragma unroll
        for (int nt = 0; nt < 4; nt++)
            #pragma unroll
            for (int r = 0; r < 4; r++) {
                const int row = bm + wr + mt * 16 + quad * 4 + r;
                const int col = bn + wc + nt * 16 + l16;
                if (BF16OUT)
                    ((unsigned short*)Cv)[(size_t)row * N + col] =
                        f2bf(acc[mt][nt][r] * cscale);
                else
                    ((float*)Cv)[(size_t)row * N + col] = acc[mt][nt][r];
            }
}

// ---------------------------------------------------------------------------
// Kernel 3: causal flash attention (R6 structure + T4 counted-vmcnt).
// 8 waves/512 thr: wq = w&3 (16 queries), wk = w>>2 (key half, 2 sub-tiles).
// Software pipeline: QK(jt) -> PV(jt-1) -> exp(jt).
// T4: per-iteration sync = s_waitcnt vmcnt(2) lgkmcnt(0) + raw s_barrier --
// the 2 newest DMAs (tile jt+1) stay IN FLIGHT across the barrier; prefetch
// distance 2 (pf(jt+2) issued after the barrier). K x3 / V x4 buffers make
// every overwrite barrier-separated from its last reader (no timing races):
//   Ks[t%3]: read QK(t) iter t | overwritten by pf(t+3) issued iter t+1.
//   Vts[t&3]: read PV(t) iter t+1 | overwritten by pf(t+4) issued iter t+2.
// lgkmcnt(0) before each barrier => all waves' ds_reads done before any DMA
// issue. Tail iteration waits vmcnt(0). Phase boundaries keep __syncthreads.
// Cross-wave O/l reduction via dead Vts scratch. LDS 64KB -> 2 blocks/CU.
// ---------------------------------------------------------------------------
__global__ __launch_bounds__(512, 4) void flash_attn_kernel(
    const unsigned short* __restrict__ qkv, const unsigned short* __restrict__ vt,
    unsigned short* __restrict__ out) {
    __shared__ unsigned short Qs[64 * 64];       // [query][dh], swizzled
    __shared__ unsigned short Ks[3][64 * 64];    // [key][dh], swizzled, x3
    __shared__ unsigned short Vts[4][64 * 64];   // [dh][key], swizzled, x4

    const int tid = threadIdx.x, lane = tid & 63, w = tid >> 6;  // w: 0..7
    const int quad = lane >> 4, l16 = lane & 15;
    const int lr8 = lane >> 3, pg8 = lane & 7;
    const int wq = w & 3;       // query sub-tile (16 rows)
    const int wk = w >> 2;      // key half (0: keys 0-31, 1: keys 32-63)
    // XCD swizzle (8 XCDs, assume round-robin bid%8): same bh -> same XCD
    const int bid = blockIdx.x;
    const int bh   = (bid & 7) * 4 + ((bid >> 3) & 3);   // 0..31
    const int pair = bid >> 5;                           // 0..15
    const int b = bh >> 4, h = bh & 15;

    const unsigned short* qb  = qkv + (size_t)(b * N_) * QKV_N + h * DH_;
    const unsigned short* kb  = qb + 1024;
    const unsigned short* vtb = vt + ((size_t)(b * 32) * 1024 + h * 64) * 64;

    bf16x4_t ones4;
    #pragma unroll
    for (int j = 0; j < 4; j++) ones4[j] = (short)0x3F80;   // bf16 1.0

    for (int phase = 0; phase < 2; phase++) {
        const int qt = phase ? (31 - pair) : pair;   // 64-query tile index
        const int qs = qt * 64;
        const int niter = qt + 1;

        __syncthreads();   // previous phase fully done (full vmcnt/lgkm drain)

        f32x4_t o[4] = {};
        f32x4_t lacc = {};
        bf16x8_t qf[2];
        bf16x4_t pf[2];    // pipelined P fragments (this wave's 2 key tiles)

        // stage tile t into Ks[t%3], Vts[t&3]: 8 waves x 8 rows each (2 DMAs)
        auto prefetch = [&](int t) {
            const int ksel = t % 3, vsel = t & 3;
            const int rb = w * 8;
            const int r  = rb + lr8;
            const int g  = pg8 ^ (r & 7);
            async16(&kb[(size_t)(t * 64 + r) * QKV_N + g * 8], &Ks[ksel][rb * 64]);
            async16(&vtb[((size_t)t * 1024 + r) * 64 + g * 8], &Vts[vsel][rb * 64]);
        };
        // S^T = K . Q^T : m = this wave's 32 keys (2 kt), n = 16 queries
        auto do_qk = [&](int kbuf, f32x4_t* s) {
            #pragma unroll
            for (int k2 = 0; k2 < 2; k2++) {
                const int g0 = k2 * 4 + quad;
                #pragma unroll
                for (int kt = 0; kt < 2; kt++) {
                    const int ktg = wk * 2 + kt;
                    const bf16x8_t a = *(const bf16x8_t*)&Ks[kbuf][
                        (ktg * 16 + l16) * 64 + (g0 ^ (l16 & 7)) * 8];
                    s[kt] = MFMA32(a, qf[k2], s[kt]);
                }
            }
        };
        // p = exp2(s); mask only on the diagonal tile. pf = A-frag of K=16 MFMA.
        auto do_exp = [&](const f32x4_t* s, int js, bool edge) {
            #pragma unroll
            for (int kt = 0; kt < 2; kt++) {
                const int ktg = wk * 2 + kt;
                float p[4];
                #pragma unroll
                for (int r = 0; r < 4; r++) {
                    float sv = s[kt][r];
                    if (edge) {
                        const int key = js + ktg * 16 + quad * 4 + r;
                        const int qy  = qs + wq * 16 + l16;
                        if (key > qy) sv = -3e38f;
                    }
                    p[r] = __builtin_amdgcn_exp2f(sv);
                }
                uint2 pk = { pk2bf(p[0], p[1]), pk2bf(p[2], p[3]) };
                pf[kt] = *(bf16x4_t*)&pk;
            }
        };
        // O += P.V ; l += P.1  (in-register A, K=16 MFMAs; partial over wk)
        auto do_pv = [&](int vbuf) {
            #pragma unroll
            for (int kt = 0; kt < 2; kt++) {
                const int ktg = wk * 2 + kt;
                const int g = ktg * 2 + (quad >> 1);
                const int col = ((g ^ (l16 & 7)) * 8) + (quad & 1) * 4;
                #pragma unroll
                for (int nt = 0; nt < 4; nt++) {
                    const bf16x4_t bv = *(const bf16x4_t*)&Vts[vbuf][
                        (nt * 16 + l16) * 64 + col];
                    o[nt] = MFMA16(pf[kt], bv, o[nt]);
                }
                lacc = MFMA16(pf[kt], ones4, lacc);
            }
        };

        // prologue: stage Q (1 DMA) + tiles 0,1 (2 DMAs each)
        {
            const int rb = w * 8;
            const int r  = rb + lr8;
            const int g  = pg8 ^ (r & 7);
            async16(&qb[(size_t)(qs + r) * QKV_N + g * 8], &Qs[rb * 64]);
        }
        prefetch(0);
        if (niter > 1) {
            prefetch(1);
            WAITBAR(2);            // Q + pf(0) done; pf(1) stays in flight
        } else {
            WAITBAR(0);
        }
        #pragma unroll
        for (int k2 = 0; k2 < 2; k2++) {
            const int g0 = k2 * 4 + quad;
            qf[k2] = *(const bf16x8_t*)&Qs[
                (wq * 16 + l16) * 64 + (g0 ^ (l16 & 7)) * 8];
        }
        {   // peeled iteration 0: QK + exp (PV deferred)
            if (2 < niter) prefetch(2);
            f32x4_t s[2] = {};
            do_qk(0, s);
            do_exp(s, 0, niter == 1);
        }

        for (int jt = 1; jt < niter; jt++) {
            // own pf(jt) complete; pf(jt+1) (2 newest) stays in flight
            if (jt + 1 < niter) WAITBAR(2); else WAITBAR(0);
            if (jt + 2 < niter) prefetch(jt + 2);
            f32x4_t s[2] = {};
            do_qk(jt % 3, s);      // current tile scores
            do_pv((jt - 1) & 3);   // previous tile PV (independent of s)
            do_exp(s, jt * 64, jt == niter - 1);
        }
        do_pv((niter - 1) & 3);    // drain the pipeline

        // cross-wave reduction: high key-half adds into low key-half, via the
        // now-dead Vts LDS (4*16*68*4B = 17.4 KB <= 32 KB). No DMAs in flight.
        __syncthreads();           // all V reads done
        float* red = (float*)&Vts[0][0];
        if (wk == 1) {
            #pragma unroll
            for (int r = 0; r < 4; r++) {
                const int q = quad * 4 + r;
                const int base = (wq * 16 + q) * 68;
                #pragma unroll
                for (int nt = 0; nt < 4; nt++)
                    red[base + nt * 16 + l16] = o[nt][r];
                red[base + 64] = lacc[r];   // same value across l16: benign race
            }
        }
        __syncthreads();
        if (wk == 0) {
            #pragma unroll
            for (int r = 0; r < 4; r++) {
                const int q = quad * 4 + r;
                const int base = (wq * 16 + q) * 68;
                #pragma unroll
                for (int nt = 0; nt < 4; nt++)
                    o[nt][r] += red[base + nt * 16 + l16];
                const float inv = 1.0f / (lacc[r] + red[base + 64]);
                const int query = qs + wq * 16 + quad * 4 + r;
                const int row = b * N_ + query;
                #pragma unroll
                for (int nt = 0; nt < 4; nt++) {
                    const int col = h * DH_ + nt * 16 + l16;
                    out[(size_t)row * (H_ * DH_) + col] = f2bf(o[nt][r] * inv);
                }
            }
        }
        // next phase's leading __syncthreads() protects red before restaging
    }
}

// ---------------------------------------------------------------------------
// Host launcher
// ---------------------------------------------------------------------------
extern "C" void kernel_launch(void* const* d_in, const int* in_sizes, int n_in,
                              void* d_out, int out_size, void* d_ws, size_t ws_size,
                              hipStream_t stream) {
    const float* x     = (const float*)d_in[0];
    const float* ln_g  = (const float*)d_in[1];
    const float* ln_b  = (const float*)d_in[2];
    const float* lnc_g = (const float*)d_in[3];
    const float* lnc_b = (const float*)d_in[4];
    const float* Wq    = (const float*)d_in[5];
    const float* Wkv   = (const float*)d_in[6];
    const float* Wo    = (const float*)d_in[7];

    char* ws = (char*)d_ws;
    const size_t MB = 1024 * 1024;
    unsigned short* qkv   = (unsigned short*)(ws + 0 * MB);    // [4096][3072] 24 MB (V region unused)
    unsigned short* vtbuf = (unsigned short*)(ws + 24 * MB);   // tiled V^T      8 MB
    unsigned short* xn    = (unsigned short*)(ws + 32 * MB);   // [4096][1024]  8 MB
    unsigned short* cn    = (unsigned short*)(ws + 40 * MB);   // [4096][1024]  8 MB
    unsigned short* wqkvT = (unsigned short*)(ws + 48 * MB);   // [3072][1024]  6 MB
    unsigned short* woT   = (unsigned short*)(ws + 54 * MB);   // [1024][1024]  2 MB
    unsigned short* ao    = xn;   // reuse: xn dead after QKV GEMM

    // LN (blocks 0..4095) + weight transposes (blocks 4096..8191), one dispatch
    ln_wt_kernel<<<8192, 256, 0, stream>>>(
        x, ln_g, ln_b, lnc_g, lnc_b, Wq, Wkv, Wo, xn, cn, wqkvT, woT);

    // fused Q+KV GEMM; Q pre-scaled; V written tiled-transposed to vtbuf
    // MINW=3: 768 blocks fully resident (3/CU), no occupancy tail
    gemm_kernel<128, true, true, 3>
        <<<dim3(QKV_N / 128, BN_ROWS / 128), 256, 0, stream>>>(
        xn, cn, wqkvT, qkv, vtbuf, BN_ROWS, QKV_N, D_);

    // paired 64-query tiles (qt, 31-qt): 512 blocks x 512 threads, 2/CU
    flash_attn_kernel<<<B_ * H_ * 16, 512, 0, stream>>>(qkv, vtbuf, ao);

    // out = ao @ woT^T (fp32 out); BM=64, 512 blocks = 2/CU (R6-proven;
    // R8's BM=128/256-block variant was 1 block/CU and regressed)
    gemm_kernel<64, false, false, 2>
        <<<dim3(D_ / 128, BN_ROWS / 64), 256, 0, stream>>>(
        ao, nullptr, woT, (float*)d_out, nullptr, BN_ROWS, D_, H_ * DH_);
}

// Round 10
// 169.348 us; speedup vs baseline: 1.1663x; 1.0768x over previous
//
#include <hip/hip_runtime.h>
#include <hip/hip_bf16.h>

// ---------------------------------------------------------------------------
// Problem constants
// ---------------------------------------------------------------------------
#define B_  2
#define N_  2048
#define D_  1024
#define H_  16
#define DH_ 64
#define BN_ROWS (B_ * N_)   // 4096
#define EPS_ 1e-5f
#define QKV_N 3072          // fused [Q | K | V] output width

typedef __attribute__((ext_vector_type(8))) short bf16x8_t;
typedef __attribute__((ext_vector_type(4))) short bf16x4_t;
typedef __attribute__((ext_vector_type(4))) float f32x4_t;

// K=16 bf16 MFMA (v_mfma_f32_16x16x16_bf16): A/B = 4 bf16 (k = quad*4+reg),
// C/D = 4 f32 (row = quad*4+r, col = l16).
#define MFMA16(a, b, c) __builtin_amdgcn_mfma_f32_16x16x16bf16_1k(a, b, c, 0, 0, 0)
#define MFMA32(a, b, c) __builtin_amdgcn_mfma_f32_16x16x32_bf16(a, b, c, 0, 0, 0)

typedef const unsigned int __attribute__((address_space(1)))* gas_ptr;
typedef unsigned int __attribute__((address_space(3)))* las_ptr;

// async global->LDS, 16B per lane, dest = wave-uniform base + lane*16
__device__ __forceinline__ void async16(const unsigned short* g, unsigned short* l) {
    __builtin_amdgcn_global_load_lds((gas_ptr)g, (las_ptr)l, 16, 0, 0);
}

__device__ __forceinline__ unsigned short f2bf(float f) {
    unsigned int u = __float_as_uint(f);
    unsigned int r = u + 0x7FFFu + ((u >> 16) & 1u);   // round-to-nearest-even
    return (unsigned short)(r >> 16);
}

// pack two f32 -> bf16x2
__device__ __forceinline__ unsigned int pk2bf(float a, float b) {
    __hip_bfloat162 t = __float22bfloat162_rn(float2{a, b});
    return *(unsigned int*)&t;
}

// ---------------------------------------------------------------------------
// Kernel 1: fused dual LayerNorm + all-weight bf16 transposes (one dispatch).
// blocks [0,4096): LN rows. blocks [4096,8192): weight transpose tiles.
// ---------------------------------------------------------------------------
__global__ __launch_bounds__(256) void ln_wt_kernel(
    const float* __restrict__ x,
    const float* __restrict__ g1, const float* __restrict__ b1,
    const float* __restrict__ g2, const float* __restrict__ b2,
    const float* __restrict__ Wq, const float* __restrict__ Wkv,
    const float* __restrict__ Wo,
    unsigned short* __restrict__ xn, unsigned short* __restrict__ cn,
    unsigned short* __restrict__ wqkvT, unsigned short* __restrict__ woT) {
    const int bid = blockIdx.x;
    const int tid = threadIdx.x;

    if (bid < BN_ROWS) {
        // ---- LayerNorm path ----
        const int row = bid;
        const float4 v = ((const float4*)(x + (size_t)row * D_))[tid];

        float s  = v.x + v.y + v.z + v.w;
        float s2 = v.x * v.x + v.y * v.y + v.z * v.z + v.w * v.w;
        #pragma unroll
        for (int off = 32; off > 0; off >>= 1) {
            s  += __shfl_down(s,  off);
            s2 += __shfl_down(s2, off);
        }
        __shared__ float red[8];
        if ((tid & 63) == 0) { red[tid >> 6] = s; red[4 + (tid >> 6)] = s2; }
        __syncthreads();
        const float S  = red[0] + red[1] + red[2] + red[3];
        const float S2 = red[4] + red[5] + red[6] + red[7];
        const float mean = S * (1.0f / D_);
        const float var  = S2 * (1.0f / D_) - mean * mean;
        const float rstd = rsqrtf(var + EPS_);

        const float4 G1 = ((const float4*)g1)[tid];
        const float4 B1 = ((const float4*)b1)[tid];
        const float4 G2 = ((const float4*)g2)[tid];
        const float4 B2 = ((const float4*)b2)[tid];

        float nx[4] = { (v.x - mean) * rstd, (v.y - mean) * rstd,
                        (v.z - mean) * rstd, (v.w - mean) * rstd };
        ushort4 o1, o2;
        o1.x = f2bf(nx[0] * G1.x + B1.x); o1.y = f2bf(nx[1] * G1.y + B1.y);
        o1.z = f2bf(nx[2] * G1.z + B1.z); o1.w = f2bf(nx[3] * G1.w + B1.w);
        o2.x = f2bf(nx[0] * G2.x + B2.x); o2.y = f2bf(nx[1] * G2.y + B2.y);
        o2.z = f2bf(nx[2] * G2.z + B2.z); o2.w = f2bf(nx[3] * G2.w + B2.w);
        ((ushort4*)(xn + (size_t)row * D_))[tid] = o1;
        ((ushort4*)(cn + (size_t)row * D_))[tid] = o2;
    } else {
        // ---- weight transpose path: fp32 [K=1024][N] -> bf16 [N][1024] ----
        const int zz = bid - BN_ROWS;           // 0..4095
        const float* src;
        unsigned short* dst;
        int N, t;
        if (zz < 1024)      { src = Wq;  dst = wqkvT;                       N = 1024; t = zz; }
        else if (zz < 3072) { src = Wkv; dst = wqkvT + (size_t)1024 * 1024; N = 2048; t = zz - 1024; }
        else                { src = Wo;  dst = woT;                         N = 1024; t = zz - 3072; }
        const int nb = N / 32;
        const int n0 = (t % nb) * 32, k0 = (t / nb) * 32;

        __shared__ float tile[32][33];
        const int tx = tid & 31, ty = tid >> 5;   // 32 x 8
        #pragma unroll
        for (int i = 0; i < 4; i++)
            tile[ty + i * 8][tx] = src[(size_t)(k0 + ty + i * 8) * N + n0 + tx];
        __syncthreads();
        #pragma unroll
        for (int i = 0; i < 4; i++)
            dst[(size_t)(n0 + ty + i * 8) * 1024 + k0 + tx] = f2bf(tile[tx][ty + i * 8]);
    }
}

// ---------------------------------------------------------------------------
// Kernel 2: bf16 GEMM (m97 structure), templated on BM, MINW, and NWAVES.
// NWAVES=4: wave grid 2x2, each (BM/2)x64  (QKV config, R6-proven).
// NWAVES=8: wave grid 2x4, each (BM/2)x32  (out-proj config: halves per-wave
//   work, 4 waves/SIMD at 2 blocks/CU -- flash R5->R6's proven mechanism).
// async global->LDS (16B) staging, XOR swizzle on the GLOBAL source address
// -> conflict-free ds_read_b128.
// FUSED (QKV): A = A0 (Q, pre-scaled 0.125*log2e) for cols<1024 else A1 (KV);
//   V region (cols>=2048) written TRANSPOSED-TILED to vt.
// ---------------------------------------------------------------------------
template <int BM, bool FUSED, bool BF16OUT, int MINW, int NWAVES>
__global__ __launch_bounds__(NWAVES * 64, MINW) void gemm_kernel(
    const unsigned short* __restrict__ A0, const unsigned short* __restrict__ A1,
    const unsigned short* __restrict__ Bt, void* __restrict__ Cv,
    unsigned short* __restrict__ vt, int M, int N, int K) {
    constexpr int WCOLS = (NWAVES == 8) ? 4 : 2;   // wave grid columns
    constexpr int WN = 128 / WCOLS, NT = WN / 16;  // per-wave N width
    constexpr int WM = BM / 2,      MT = WM / 16;  // per-wave M height
    constexpr int AI = BM / (8 * NWAVES);          // A stage chunks per wave
    constexpr int BI = 128 / (8 * NWAVES);         // B stage chunks per wave
    __shared__ unsigned short As[BM * 64];
    __shared__ unsigned short Bs[128 * 64];
    const int tid = threadIdx.x, lane = tid & 63, w = tid >> 6;
    const int quad = lane >> 4, l16 = lane & 15;
    const int lr8 = lane >> 3, pg8 = lane & 7;
    const int wr = (w / WCOLS) * WM, wc = (w % WCOLS) * WN;
    const int bm = blockIdx.y * BM, bn = blockIdx.x * 128;
    const unsigned short* A = (FUSED && bn >= 1024) ? A1 : A0;
    const float cscale = (FUSED && bn < 1024) ? 0.180336880111120f : 1.0f;

    f32x4_t acc[MT][NT] = {};
    for (int k0 = 0; k0 < K; k0 += 64) {
        #pragma unroll
        for (int i = 0; i < AI; i++) {
            const int rb = w * (BM / NWAVES) + i * 8;
            const int r  = rb + lr8;
            const int g  = pg8 ^ (r & 7);
            async16(&A[(size_t)(bm + r) * K + k0 + g * 8], &As[rb * 64]);
        }
        #pragma unroll
        for (int i = 0; i < BI; i++) {
            const int rb = w * (128 / NWAVES) + i * 8;
            const int r  = rb + lr8;
            const int g  = pg8 ^ (r & 7);
            async16(&Bt[(size_t)(bn + r) * K + k0 + g * 8], &Bs[rb * 64]);
        }
        __syncthreads();
        #pragma unroll
        for (int kk = 0; kk < 64; kk += 32) {
            bf16x8_t af[MT], bfr[NT];
            const int g0 = (kk >> 3) + quad;
            #pragma unroll
            for (int t = 0; t < MT; t++)
                af[t] = *(const bf16x8_t*)&As[(wr + t * 16 + l16) * 64 +
                                              ((g0 ^ (l16 & 7)) * 8)];
            #pragma unroll
            for (int t = 0; t < NT; t++)
                bfr[t] = *(const bf16x8_t*)&Bs[(wc + t * 16 + l16) * 64 +
                                               ((g0 ^ (l16 & 7)) * 8)];
            #pragma unroll
            for (int mt = 0; mt < MT; mt++)
                #pragma unroll
                for (int nt = 0; nt < NT; nt++)
                    acc[mt][nt] = MFMA32(af[mt], bfr[nt], acc[mt][nt]);
        }
        __syncthreads();
    }

    if (FUSED && bn >= 2048) {
        // V region -> tiled transpose into vt. Wave tile = WM seq x WN cols.
        const int seq0 = bm + wr;                 // multiple of 64 (WM=64)
        const int bq = seq0 >> 11;                // batch
        const int kt = (seq0 & (N_ - 1)) >> 6;    // 64-key tile within batch
        #pragma unroll
        for (int nt = 0; nt < NT; nt++) {
            const int c = (bn - 2048) + wc + nt * 16 + l16;   // 0..1023
            unsigned short* dst =
                vt + (((size_t)(bq * 32 + kt) * 1024) + c) * 64;
            #pragma unroll
            for (int mt = 0; mt < MT; mt++) {
                uint2 v2 = { pk2bf(acc[mt][nt][0], acc[mt][nt][1]),
                             pk2bf(acc[mt][nt][2], acc[mt][nt][3]) };
                *(uint2*)&dst[mt * 16 + quad * 4] = v2;   // 4 consecutive keys
            }
        }
        return;
    }

    #pragma unroll
    for (int mt = 0; mt < MT; mt++)
        #pragma unroll
        for (int nt = 0; nt < NT; nt++)
            #pragma unroll
            for (int r = 0; r < 4; r++) {
                const int row = bm + wr + mt * 16 + quad * 4 + r;
                const int col = bn + wc + nt * 16 + l16;
                if (BF16OUT)
                    ((unsigned short*)Cv)[(size_t)row * N + col] =
                        f2bf(acc[mt][nt][r] * cscale);
                else
                    ((float*)Cv)[(size_t)row * N + col] = acc[mt][nt][r];
            }
}

// ---------------------------------------------------------------------------
// Kernel 3: causal flash attention, S^T scheme, software-pipelined
// (QK(jt) -> PV(jt-1) -> exp(jt)), 8 WAVES / 512 THREADS per block:
// key dimension split across wave halves (wk = w>>2): waves w and w+4 share
// the same 16 queries (wq = w&3), each handles 2 of 4 key sub-tiles.
// -> 4 waves/SIMD (vs 2) to fill the lgkm/barrier stalls; per-wave work
// halves; one cross-wave O/l reduction per phase through the dead Vts LDS.
// V triple-buffered; K double-buffered. exp via raw v_exp_f32.
// XCD-aware swizzle; paired (qt, 31-qt) tiles: 512 blocks = 2/CU, balanced.
// (Round-6 version verbatim -- R7 global-K, R9 counted-vmcnt both regressed.)
// ---------------------------------------------------------------------------
__global__ __launch_bounds__(512, 4) void flash_attn_kernel(
    const unsigned short* __restrict__ qkv, const unsigned short* __restrict__ vt,
    unsigned short* __restrict__ out) {
    __shared__ unsigned short Qs[64 * 64];       // [query][dh], swizzled
    __shared__ unsigned short Ks[2][64 * 64];    // [key][dh], swizzled, dbuf
    __shared__ unsigned short Vts[3][64 * 64];   // [dh][key], swizzled, tribuf

    const int tid = threadIdx.x, lane = tid & 63, w = tid >> 6;  // w: 0..7
    const int quad = lane >> 4, l16 = lane & 15;
    const int lr8 = lane >> 3, pg8 = lane & 7;
    const int wq = w & 3;       // query sub-tile (16 rows)
    const int wk = w >> 2;      // key half (0: keys 0-31, 1: keys 32-63)
    // XCD swizzle (8 XCDs, assume round-robin bid%8): same bh -> same XCD
    const int bid = blockIdx.x;
    const int bh   = (bid & 7) * 4 + ((bid >> 3) & 3);   // 0..31
    const int pair = bid >> 5;                           // 0..15
    const int b = bh >> 4, h = bh & 15;

    const unsigned short* qb  = qkv + (size_t)(b * N_) * QKV_N + h * DH_;
    const unsigned short* kb  = qb + 1024;
    const unsigned short* vtb = vt + ((size_t)(b * 32) * 1024 + h * 64) * 64;

    bf16x4_t ones4;
    #pragma unroll
    for (int j = 0; j < 4; j++) ones4[j] = (short)0x3F80;   // bf16 1.0

    for (int phase = 0; phase < 2; phase++) {
        const int qt = phase ? (31 - pair) : pair;   // 64-query tile index
        const int qs = qt * 64;
        const int niter = qt + 1;

        __syncthreads();   // previous phase fully done with Qs/Ks/Vts (incl red)

        f32x4_t o[4] = {};
        f32x4_t lacc = {};
        bf16x8_t qf[2];
        bf16x4_t pf[2];    // pipelined P fragments (this wave's 2 key tiles)

        // stage tile t into K[t&1], V[t%3]: 8 waves x 8 rows each
        auto prefetch = [&](int t) {
            const int ksel = t & 1, vsel = t % 3;
            const int rb = w * 8;
            const int r  = rb + lr8;
            const int g  = pg8 ^ (r & 7);
            async16(&kb[(size_t)(t * 64 + r) * QKV_N + g * 8], &Ks[ksel][rb * 64]);
            async16(&vtb[((size_t)t * 1024 + r) * 64 + g * 8], &Vts[vsel][rb * 64]);
        };
        // S^T = K . Q^T : m = this wave's 32 keys (2 kt), n = 16 queries
        auto do_qk = [&](int kbuf, f32x4_t* s) {
            #pragma unroll
            for (int k2 = 0; k2 < 2; k2++) {
                const int g0 = k2 * 4 + quad;
                #pragma unroll
                for (int kt = 0; kt < 2; kt++) {
                    const int ktg = wk * 2 + kt;
                    const bf16x8_t a = *(const bf16x8_t*)&Ks[kbuf][
                        (ktg * 16 + l16) * 64 + (g0 ^ (l16 & 7)) * 8];
                    s[kt] = MFMA32(a, qf[k2], s[kt]);
                }
            }
        };
        // p = exp2(s); mask only on the diagonal tile. pf = A-frag of K=16 MFMA.
        auto do_exp = [&](const f32x4_t* s, int js, bool edge) {
            #pragma unroll
            for (int kt = 0; kt < 2; kt++) {
                const int ktg = wk * 2 + kt;
                float p[4];
                #pragma unroll
                for (int r = 0; r < 4; r++) {
                    float sv = s[kt][r];
                    if (edge) {
                        const int key = js + ktg * 16 + quad * 4 + r;
                        const int qy  = qs + wq * 16 + l16;
                        if (key > qy) sv = -3e38f;
                    }
                    p[r] = __builtin_amdgcn_exp2f(sv);
                }
                uint2 pk = { pk2bf(p[0], p[1]), pk2bf(p[2], p[3]) };
                pf[kt] = *(bf16x4_t*)&pk;
            }
        };
        // O += P.V ; l += P.1  (in-register A, K=16 MFMAs; partial over wk)
        auto do_pv = [&](int vbuf) {
            #pragma unroll
            for (int kt = 0; kt < 2; kt++) {
                const int ktg = wk * 2 + kt;
                const int g = ktg * 2 + (quad >> 1);
                const int col = ((g ^ (l16 & 7)) * 8) + (quad & 1) * 4;
                #pragma unroll
                for (int nt = 0; nt < 4; nt++) {
                    const bf16x4_t bv = *(const bf16x4_t*)&Vts[vbuf][
                        (nt * 16 + l16) * 64 + col];
                    o[nt] = MFMA16(pf[kt], bv, o[nt]);
                }
                lacc = MFMA16(pf[kt], ones4, lacc);
            }
        };

        // stage Q + tile 0
        {
            const int rb = w * 8;
            const int r  = rb + lr8;
            const int g  = pg8 ^ (r & 7);
            async16(&qb[(size_t)(qs + r) * QKV_N + g * 8], &Qs[rb * 64]);
        }
        prefetch(0);
        __syncthreads();           // drain Q + tile 0

        if (niter > 1) prefetch(1);
        #pragma unroll
        for (int k2 = 0; k2 < 2; k2++) {
            const int g0 = k2 * 4 + quad;
            qf[k2] = *(const bf16x8_t*)&Qs[
                (wq * 16 + l16) * 64 + (g0 ^ (l16 & 7)) * 8];
        }
        {   // peeled iteration 0: QK + exp (PV deferred)
            f32x4_t s[2] = {};
            do_qk(0, s);
            do_exp(s, 0, niter == 1);
        }

        for (int jt = 1; jt < niter; jt++) {
            __syncthreads();       // drains prefetch(jt); prior reads done
            if (jt + 1 < niter) prefetch(jt + 1);
            f32x4_t s[2] = {};
            do_qk(jt & 1, s);      // current tile scores
            do_pv((jt - 1) % 3);   // previous tile PV (independent of s)
            do_exp(s, jt * 64, jt == niter - 1);
        }
        do_pv((niter - 1) % 3);    // drain the pipeline

        // cross-wave reduction: high key-half adds into low key-half, via the
        // now-dead Vts LDS (4*16*68*4B = 17.4 KB <= 24 KB).
        __syncthreads();           // all V reads done
        float* red = (float*)&Vts[0][0];
        if (wk == 1) {
            #pragma unroll
            for (int r = 0; r < 4; r++) {
                const int q = quad * 4 + r;
                const int base = (wq * 16 + q) * 68;
                #pragma unroll
                for (int nt = 0; nt < 4; nt++)
                    red[base + nt * 16 + l16] = o[nt][r];
                red[base + 64] = lacc[r];   // same value across l16: benign race
            }
        }
        __syncthreads();
        if (wk == 0) {
            #pragma unroll
            for (int r = 0; r < 4; r++) {
                const int q = quad * 4 + r;
                const int base = (wq * 16 + q) * 68;
                #pragma unroll
                for (int nt = 0; nt < 4; nt++)
                    o[nt][r] += red[base + nt * 16 + l16];
                const float inv = 1.0f / (lacc[r] + red[base + 64]);
                const int query = qs + wq * 16 + quad * 4 + r;
                const int row = b * N_ + query;
                #pragma unroll
                for (int nt = 0; nt < 4; nt++) {
                    const int col = h * DH_ + nt * 16 + l16;
                    out[(size_t)row * (H_ * DH_) + col] = f2bf(o[nt][r] * inv);
                }
            }
        }
        // next phase's leading __syncthreads() protects red before restaging
    }
}

// ---------------------------------------------------------------------------
// Host launcher
// ---------------------------------------------------------------------------
extern "C" void kernel_launch(void* const* d_in, const int* in_sizes, int n_in,
                              void* d_out, int out_size, void* d_ws, size_t ws_size,
                              hipStream_t stream) {
    const float* x     = (const float*)d_in[0];
    const float* ln_g  = (const float*)d_in[1];
    const float* ln_b  = (const float*)d_in[2];
    const float* lnc_g = (const float*)d_in[3];
    const float* lnc_b = (const float*)d_in[4];
    const float* Wq    = (const float*)d_in[5];
    const float* Wkv   = (const float*)d_in[6];
    const float* Wo    = (const float*)d_in[7];

    char* ws = (char*)d_ws;
    const size_t MB = 1024 * 1024;
    unsigned short* qkv   = (unsigned short*)(ws + 0 * MB);    // [4096][3072] 24 MB (V region unused)
    unsigned short* vtbuf = (unsigned short*)(ws + 24 * MB);   // tiled V^T      8 MB
    unsigned short* xn    = (unsigned short*)(ws + 32 * MB);   // [4096][1024]  8 MB
    unsigned short* cn    = (unsigned short*)(ws + 40 * MB);   // [4096][1024]  8 MB
    unsigned short* wqkvT = (unsigned short*)(ws + 48 * MB);   // [3072][1024]  6 MB
    unsigned short* woT   = (unsigned short*)(ws + 54 * MB);   // [1024][1024]  2 MB
    unsigned short* ao    = xn;   // reuse: xn dead after QKV GEMM

    // LN (blocks 0..4095) + weight transposes (blocks 4096..8191), one dispatch
    ln_wt_kernel<<<8192, 256, 0, stream>>>(
        x, ln_g, ln_b, lnc_g, lnc_b, Wq, Wkv, Wo, xn, cn, wqkvT, woT);

    // fused Q+KV GEMM; Q pre-scaled; V written tiled-transposed to vtbuf
    // 4 waves, MINW=3: 768 blocks fully resident (3/CU), no occupancy tail
    gemm_kernel<128, true, true, 3, 4>
        <<<dim3(QKV_N / 128, BN_ROWS / 128), 256, 0, stream>>>(
        xn, cn, wqkvT, qkv, vtbuf, BN_ROWS, QKV_N, D_);

    // paired 64-query tiles (qt, 31-qt): 512 blocks x 512 threads, 2/CU
    flash_attn_kernel<<<B_ * H_ * 16, 512, 0, stream>>>(qkv, vtbuf, ao);

    // out = ao @ woT^T (fp32 out); BM=64, 8 WAVES (2x4 wave grid, 32x32 per
    // wave): 512 blocks x 512 thr = 2 blocks/CU -> 4 waves/SIMD (was 2).
    gemm_kernel<64, false, false, 4, 8>
        <<<dim3(D_ / 128, BN_ROWS / 64), 512, 0, stream>>>(
        ao, nullptr, woT, (float*)d_out, nullptr, BN_ROWS, D_, H_ * DH_);
}